// Round 5
// baseline (1322.160 us; speedup 1.0000x reference)
//
#include <hip/hip_runtime.h>

// ---------------------------------------------------------------------------
// GCN: 4 layers of  h' = A_hat_norm (h @ W) + b   on fixed graph, fp32.
// g = (h@W) * dinv[row]  (GEMM epilogue), then per-dst:
//   h'[dst] = dinv[dst] * ( g[dst] + sum_{src in N(dst)} g[src] ) + b
// R2: gemm spill fixed. R3: CSR fill via binned counting sort.
// R4: per-node degree/scan/fill all in LDS per 256-node bin.
// R5: aggregation feature-chunked + XCD-affine. R4 agg fetched 362MB/layer
// (random 256B gathers over 25.6MB G; no per-XCD L2 fit). Now G and
// intermediate activations live in chunked layout [8][N][8 floats]:
// chunk = 3.2MB < 4MB per-XCD L2, agg blocks pin chunk c to XCD c via
// blockIdx&7 -> gathers become L2 hits. GEMM reads/writes chunked.
// Final layer writes row-major Y + separate out-projection pass.
// ---------------------------------------------------------------------------

#define FEAT 128
#define EMB 64
#define BINSHIFT 8
#define BINSIZE 256
#define NBIN 391          // ceil(100000/256)
#define CHUNK 8192

// ---------------- CSR build ----------------

__global__ void zero_k(int* __restrict__ p, int n) {
    int i = blockIdx.x * blockDim.x + threadIdx.x;
    if (i < n) p[i] = 0;
}

// Pass A: per-bin edge counts. LDS histogram per chunk.
__global__ __launch_bounds__(256) void bin_count_k(
    const int* __restrict__ dst, int* __restrict__ bincnt, int E) {
    __shared__ int hist[NBIN];
    int t = threadIdx.x;
    int base = blockIdx.x * CHUNK;
    int end = min(base + CHUNK, E);
    for (int i = t; i < NBIN; i += 256) hist[i] = 0;
    __syncthreads();
    for (int e = base + t; e < end; e += 256)
        atomicAdd(&hist[dst[e] >> BINSHIFT], 1);
    __syncthreads();
    for (int b = t; b < NBIN; b += 256) {
        int c = hist[b];
        if (c > 0) atomicAdd(&bincnt[b], c);
    }
}

// exclusive scan of bin counts (NBIN <= 512), writes binptr + bincur.
__global__ void binscan_k(const int* __restrict__ bincnt, int* __restrict__ binptr,
                          int* __restrict__ bincur, int nbin, int E) {
    __shared__ int s[512];
    int t = threadIdx.x;
    int v = (t < nbin) ? bincnt[t] : 0;
    s[t] = v;
    __syncthreads();
    for (int off = 1; off < 512; off <<= 1) {
        int tv = (t >= off) ? s[t - off] : 0;
        __syncthreads();
        s[t] += tv;
        __syncthreads();
    }
    if (t < nbin) {
        int excl = s[t] - v;
        binptr[t] = excl;
        bincur[t] = excl;
    }
    if (t == 0) binptr[nbin] = E;
}

// Pass B: scatter edges into dst-range bins. One block per 8192-edge chunk.
// Output word: src | (dst&255)<<24  (src < 2^17 fits in 24 bits).
__global__ __launch_bounds__(256) void bin_edges_k(
    const int* __restrict__ src, const int* __restrict__ dst,
    int* __restrict__ bincur, int* __restrict__ ebuf, int E) {
    __shared__ int hist[NBIN];
    __shared__ int lcur[NBIN];
    int t = threadIdx.x;
    int base = blockIdx.x * CHUNK;
    int end = min(base + CHUNK, E);
    for (int i = t; i < NBIN; i += 256) hist[i] = 0;
    __syncthreads();
    for (int e = base + t; e < end; e += 256)
        atomicAdd(&hist[dst[e] >> BINSHIFT], 1);
    __syncthreads();
    for (int b = t; b < NBIN; b += 256) {
        int c = hist[b];
        lcur[b] = (c > 0) ? atomicAdd(&bincur[b], c) : 0;
    }
    __syncthreads();
    for (int e = base + t; e < end; e += 256) {
        int d = dst[e];
        int bin = d >> BINSHIFT;
        int r = atomicAdd(&lcur[bin], 1);
        ebuf[r] = src[e] | ((d & (BINSIZE - 1)) << 24);
    }
}

// Pass C: one block per bin. LDS degree count -> LDS scan -> rowptr/dinv
// writes -> col scatter with LDS cursors. No global per-node atomics.
__global__ __launch_bounds__(256) void build_csr_k(
    const int* __restrict__ ebuf, const int* __restrict__ binptr,
    int* __restrict__ rowptr, float* __restrict__ dinv,
    int* __restrict__ col, int N, int E, int nbin) {
    __shared__ int lcnt[BINSIZE];
    __shared__ int lscan[BINSIZE];
    __shared__ int lcur[BINSIZE];
    int b = blockIdx.x;
    int t = threadIdx.x;
    int n0 = b << BINSHIFT;
    int e0 = binptr[b];
    int e1 = binptr[b + 1];

    lcnt[t] = 0;
    __syncthreads();
    for (int i = e0 + t; i < e1; i += 256)
        atomicAdd(&lcnt[((unsigned)ebuf[i]) >> 24], 1);
    __syncthreads();

    int v = lcnt[t];
    lscan[t] = v;
    __syncthreads();
    for (int off = 1; off < 256; off <<= 1) {
        int tv = (t >= off) ? lscan[t - off] : 0;
        __syncthreads();
        lscan[t] += tv;
        __syncthreads();
    }
    int excl = e0 + lscan[t] - v;
    lcur[t] = excl;
    if (n0 + t < N) {
        rowptr[n0 + t] = excl;
        dinv[n0 + t] = 1.0f / sqrtf((float)(v + 1));
    }
    if (b == nbin - 1 && t == 0) rowptr[N] = E;
    __syncthreads();

    for (int i = e0 + t; i < e1; i += 256) {
        int w = ebuf[i];
        int dl = ((unsigned)w) >> 24;
        int p = atomicAdd(&lcur[dl], 1);
        col[p] = w & 0xFFFFFF;
    }
}

// ---------------- GEMM + dinv row-scale, chunked output ----------------
// G layout: [8 chunks][N][8 floats]; element (n,j) at ((j>>3)*N + n)*8 + (j&7).
// CHIN: input H also chunked (intermediate layers); else row-major [N][K].
template <int K, bool CHIN>
__global__ __launch_bounds__(256, 4) void gemm_scale_k(
    const float* __restrict__ H, const float* __restrict__ W,
    const float* __restrict__ dinv, float* __restrict__ G, int N) {
    __shared__ float Ws[K * EMB];
    int t = threadIdx.x;
    for (int i = t * 4; i < K * EMB; i += 1024) {
        *(float4*)(Ws + i) = *(const float4*)(W + i);
    }
    __syncthreads();

    int tc = t & 15;   // col group -> 4 cols
    int tr = t >> 4;   // row group -> 4 rows
    int j0 = tc * 4;
    int r0 = blockIdx.x * 64 + tr * 4;
    if (r0 >= N) return;

    int r[4];
#pragma unroll
    for (int i = 0; i < 4; i++) r[i] = (r0 + i < N) ? (r0 + i) : (N - 1);

#define ALOAD(i, k) (CHIN ? *(const float4*)(H + ((size_t)((k) >> 3) * N + r[i]) * 8 + ((k) & 7)) \
                          : *(const float4*)(H + (size_t)r[i] * K + (k)))

    float acc[4][4] = {{0.f}};
    float4 a[4], an[4];
#pragma unroll
    for (int i = 0; i < 4; i++) a[i] = ALOAD(i, 0);

#pragma unroll 1
    for (int k = 0; k < K; k += 4) {
        if (k + 4 < K) {
#pragma unroll
            for (int i = 0; i < 4; i++) an[i] = ALOAD(i, k + 4);
        }
#pragma unroll
        for (int kk = 0; kk < 4; kk++) {
            float4 wv = *(const float4*)(Ws + (k + kk) * EMB + j0);
#pragma unroll
            for (int i = 0; i < 4; i++) {
                float av = (kk == 0) ? a[i].x : (kk == 1) ? a[i].y : (kk == 2) ? a[i].z : a[i].w;
                acc[i][0] = fmaf(av, wv.x, acc[i][0]);
                acc[i][1] = fmaf(av, wv.y, acc[i][1]);
                acc[i][2] = fmaf(av, wv.z, acc[i][2]);
                acc[i][3] = fmaf(av, wv.w, acc[i][3]);
            }
        }
#pragma unroll
        for (int i = 0; i < 4; i++) a[i] = an[i];
    }
#undef ALOAD

#pragma unroll
    for (int i = 0; i < 4; i++) {
        if (r0 + i < N) {
            float s = dinv[r0 + i];
            float4 o = make_float4(acc[i][0] * s, acc[i][1] * s, acc[i][2] * s, acc[i][3] * s);
            *(float4*)(G + ((size_t)(j0 >> 3) * N + (r0 + i)) * 8 + (j0 & 7)) = o;
        }
    }
}

// ---------------- Chunked aggregation: wave per (node, chunk) ----------------
// chunk = blockIdx&7 -> XCD round-robin affinity; each XCD's 3.2MB G-chunk
// stays resident in its 4MB L2, so gathers are L2 hits.
// Lane map: esub = lane>>3 (8 edges in parallel), f = lane&7 (8 feats).

__device__ __forceinline__ float agg_chunk_node(
    const float* __restrict__ Gc, const int* __restrict__ col,
    int s, int e, int node, int esub, int f) {
    float acc0 = 0.f, acc1 = 0.f;
    if (esub == 0) acc0 = Gc[(size_t)node * 8 + f];  // self loop
    int i = s;
    for (; i + 16 <= e; i += 16) {
        int ca = col[i + esub];
        int cb = col[i + 8 + esub];
        acc0 += Gc[(size_t)ca * 8 + f];
        acc1 += Gc[(size_t)cb * 8 + f];
    }
    for (; i < e; i += 8) {
        int j = i + esub;
        if (j < e) acc0 += Gc[(size_t)col[j] * 8 + f];
    }
    float acc = acc0 + acc1;
    acc += __shfl_down(acc, 32, 64);
    acc += __shfl_down(acc, 16, 64);
    acc += __shfl_down(acc, 8, 64);
    return acc;  // valid in lanes 0..7
}

__global__ __launch_bounds__(256) void agg_chunk_k(
    const float* __restrict__ G, const float* __restrict__ dinv,
    const int* __restrict__ rowptr, const int* __restrict__ col,
    const float* __restrict__ bias, float* __restrict__ Hout,  // chunked
    int N) {
    int chunk = blockIdx.x & 7;
    int node = (blockIdx.x >> 3) * 4 + (threadIdx.x >> 6);
    if (node >= N) return;
    int lane = threadIdx.x & 63;
    int esub = lane >> 3, f = lane & 7;
    const float* Gc = G + (size_t)chunk * N * 8;
    int s = rowptr[node], e = rowptr[node + 1];
    float acc = agg_chunk_node(Gc, col, s, e, node, esub, f);
    if (lane < 8) {
        Hout[((size_t)chunk * N + node) * 8 + f] = acc * dinv[node] + bias[chunk * 8 + f];
    }
}

// Final layer: write row-major Y (harness layout).
__global__ __launch_bounds__(256) void agg_chunk_final_k(
    const float* __restrict__ G, const float* __restrict__ dinv,
    const int* __restrict__ rowptr, const int* __restrict__ col,
    const float* __restrict__ bias, float* __restrict__ Y,  // row-major [N][64]
    int N) {
    int chunk = blockIdx.x & 7;
    int node = (blockIdx.x >> 3) * 4 + (threadIdx.x >> 6);
    if (node >= N) return;
    int lane = threadIdx.x & 63;
    int esub = lane >> 3, f = lane & 7;
    const float* Gc = G + (size_t)chunk * N * 8;
    int s = rowptr[node], e = rowptr[node + 1];
    float acc = agg_chunk_node(Gc, col, s, e, node, esub, f);
    if (lane < 8) {
        Y[(size_t)node * EMB + chunk * 8 + f] = acc * dinv[node] + bias[chunk * 8 + f];
    }
}

// Out = Y @ Wout + bout. Wave per node.
__global__ __launch_bounds__(256) void out_proj_k(
    const float* __restrict__ Y, const float* __restrict__ Wout,
    const float* __restrict__ bout, float* __restrict__ Out, int N) {
    int gw = (blockIdx.x * 256 + threadIdx.x) >> 6;
    int lane = threadIdx.x & 63;
    if (gw >= N) return;
    float p = Y[(size_t)gw * EMB + lane] * Wout[lane];
#pragma unroll
    for (int off = 32; off > 0; off >>= 1) p += __shfl_down(p, off, 64);
    if (lane == 0) Out[gw] = p + bout[0];
}

// ---------------- launch ----------------

extern "C" void kernel_launch(void* const* d_in, const int* in_sizes, int n_in,
                              void* d_out, int out_size, void* d_ws, size_t ws_size,
                              hipStream_t stream) {
    const float* x    = (const float*)d_in[0];
    const int*   ei   = (const int*)d_in[1];
    const float* W0   = (const float*)d_in[3];
    const float* b0   = (const float*)d_in[4];
    const float* W1   = (const float*)d_in[5];
    const float* b1   = (const float*)d_in[6];
    const float* W2   = (const float*)d_in[7];
    const float* b2   = (const float*)d_in[8];
    const float* W3   = (const float*)d_in[9];
    const float* b3   = (const float*)d_in[10];
    const float* Wout = (const float*)d_in[11];
    const float* bout = (const float*)d_in[12];

    const int N = in_sizes[0] / FEAT;      // 100000
    const int E = in_sizes[1] / 2;         // 3200000
    const int* srcp = ei;                  // edge_index[0]
    const int* dstp = ei + E;              // edge_index[1]
    const int nbin = (N + BINSIZE - 1) / BINSIZE;   // 391

    // workspace layout (regions padded to 64 elems for float4 alignment)
    const int NP = ((N + 64) + 63) / 64 * 64;   // holds N+1
    float* dinv  = (float*)d_ws;
    int* rowptr  = (int*)(dinv + NP);
    int* bincnt  = rowptr + NP;
    int* binptr  = bincnt + 1024;
    int* bincur  = binptr + 1024;
    int* col     = bincur + 1024;
    float* bufA  = (float*)(col + ((E + 63) / 64) * 64);  // chunked G
    int* ebuf    = (int*)bufA;            // aliased: ebuf dead before first gemm

    float* Out = (float*)d_out;
    float* Y   = Out + N;                 // y-region: chunked mid-layers, row-major at end

    const int gemm_blocks = (N + 63) / 64;
    const int aggc_blocks = ((N + 3) / 4) * 8;   // (node-blocks) x 8 chunks
    const int proj_blocks = (N + 3) / 4;
    const int nchunk = (E + CHUNK - 1) / CHUNK;

    // --- CSR build ---
    zero_k<<<1, 1024, 0, stream>>>(bincnt, 1024);
    bin_count_k<<<nchunk, 256, 0, stream>>>(dstp, bincnt, E);
    binscan_k<<<1, 512, 0, stream>>>(bincnt, binptr, bincur, nbin, E);
    bin_edges_k<<<nchunk, 256, 0, stream>>>(srcp, dstp, bincur, ebuf, E);
    build_csr_k<<<nbin, 256, 0, stream>>>(ebuf, binptr, rowptr, dinv, col, N, E, nbin);

    // --- layer 0 (K=128, row-major in, chunked out) ---
    gemm_scale_k<FEAT, false><<<gemm_blocks, 256, 0, stream>>>(x, W0, dinv, bufA, N);
    agg_chunk_k<<<aggc_blocks, 256, 0, stream>>>(bufA, dinv, rowptr, col, b0, Y, N);
    // --- layer 1 ---
    gemm_scale_k<EMB, true><<<gemm_blocks, 256, 0, stream>>>(Y, W1, dinv, bufA, N);
    agg_chunk_k<<<aggc_blocks, 256, 0, stream>>>(bufA, dinv, rowptr, col, b1, Y, N);
    // --- layer 2 ---
    gemm_scale_k<EMB, true><<<gemm_blocks, 256, 0, stream>>>(Y, W2, dinv, bufA, N);
    agg_chunk_k<<<aggc_blocks, 256, 0, stream>>>(bufA, dinv, rowptr, col, b2, Y, N);
    // --- layer 3: row-major Y out + projection ---
    gemm_scale_k<EMB, true><<<gemm_blocks, 256, 0, stream>>>(Y, W3, dinv, bufA, N);
    agg_chunk_final_k<<<aggc_blocks, 256, 0, stream>>>(bufA, dinv, rowptr, col, b3, Y, N);
    out_proj_k<<<proj_blocks, 256, 0, stream>>>(Y, Wout, bout, Out, N);
}

// Round 6
// 1258.031 us; speedup vs baseline: 1.0510x; 1.0510x over previous
//
#include <hip/hip_runtime.h>

// ---------------------------------------------------------------------------
// GCN: 4 layers of  h' = A_hat_norm (h @ W) + b   on fixed graph, fp32.
// g = (h@W) * dinv[row]  (GEMM epilogue), then per-dst:
//   h'[dst] = dinv[dst] * ( g[dst] + sum_{src in N(dst)} g[src] ) + b
// R2: gemm spill fixed. R3: CSR fill via binned counting sort.
// R4: per-node degree/scan/fill all in LDS per 256-node bin.
// R5: feature-chunked G [8][N][8] + XCD affinity (blockIdx&7): agg L2-miss
// traffic 362->77MB -- but 800K tiny waves made it latency-bound (265us).
// R6: agg reshaped: 8 node-slots per wave (slot=lane>>3, f=lane&7), each
// slot register-accumulates its node's 8 chunk-features over its edge list;
// 4 node-groups per wave sequentially -> 25K long waves, 256B coalesced
// stores, zero shuffles. Traffic unchanged, latency hidden.
// ---------------------------------------------------------------------------

#define FEAT 128
#define EMB 64
#define BINSHIFT 8
#define BINSIZE 256
#define NBIN 391          // ceil(100000/256)
#define CHUNK 8192
#define AGG_GROUPS 4      // node-groups of 8 per wave

// ---------------- CSR build ----------------

__global__ void zero_k(int* __restrict__ p, int n) {
    int i = blockIdx.x * blockDim.x + threadIdx.x;
    if (i < n) p[i] = 0;
}

// Pass A: per-bin edge counts. LDS histogram per chunk.
__global__ __launch_bounds__(256) void bin_count_k(
    const int* __restrict__ dst, int* __restrict__ bincnt, int E) {
    __shared__ int hist[NBIN];
    int t = threadIdx.x;
    int base = blockIdx.x * CHUNK;
    int end = min(base + CHUNK, E);
    for (int i = t; i < NBIN; i += 256) hist[i] = 0;
    __syncthreads();
    for (int e = base + t; e < end; e += 256)
        atomicAdd(&hist[dst[e] >> BINSHIFT], 1);
    __syncthreads();
    for (int b = t; b < NBIN; b += 256) {
        int c = hist[b];
        if (c > 0) atomicAdd(&bincnt[b], c);
    }
}

// exclusive scan of bin counts (NBIN <= 512), writes binptr + bincur.
__global__ void binscan_k(const int* __restrict__ bincnt, int* __restrict__ binptr,
                          int* __restrict__ bincur, int nbin, int E) {
    __shared__ int s[512];
    int t = threadIdx.x;
    int v = (t < nbin) ? bincnt[t] : 0;
    s[t] = v;
    __syncthreads();
    for (int off = 1; off < 512; off <<= 1) {
        int tv = (t >= off) ? s[t - off] : 0;
        __syncthreads();
        s[t] += tv;
        __syncthreads();
    }
    if (t < nbin) {
        int excl = s[t] - v;
        binptr[t] = excl;
        bincur[t] = excl;
    }
    if (t == 0) binptr[nbin] = E;
}

// Pass B: scatter edges into dst-range bins. One block per 8192-edge chunk.
// Output word: src | (dst&255)<<24  (src < 2^17 fits in 24 bits).
__global__ __launch_bounds__(256) void bin_edges_k(
    const int* __restrict__ src, const int* __restrict__ dst,
    int* __restrict__ bincur, int* __restrict__ ebuf, int E) {
    __shared__ int hist[NBIN];
    __shared__ int lcur[NBIN];
    int t = threadIdx.x;
    int base = blockIdx.x * CHUNK;
    int end = min(base + CHUNK, E);
    for (int i = t; i < NBIN; i += 256) hist[i] = 0;
    __syncthreads();
    for (int e = base + t; e < end; e += 256)
        atomicAdd(&hist[dst[e] >> BINSHIFT], 1);
    __syncthreads();
    for (int b = t; b < NBIN; b += 256) {
        int c = hist[b];
        lcur[b] = (c > 0) ? atomicAdd(&bincur[b], c) : 0;
    }
    __syncthreads();
    for (int e = base + t; e < end; e += 256) {
        int d = dst[e];
        int bin = d >> BINSHIFT;
        int r = atomicAdd(&lcur[bin], 1);
        ebuf[r] = src[e] | ((d & (BINSIZE - 1)) << 24);
    }
}

// Pass C: one block per bin. LDS degree count -> LDS scan -> rowptr/dinv
// writes -> col scatter with LDS cursors. No global per-node atomics.
__global__ __launch_bounds__(256) void build_csr_k(
    const int* __restrict__ ebuf, const int* __restrict__ binptr,
    int* __restrict__ rowptr, float* __restrict__ dinv,
    int* __restrict__ col, int N, int E, int nbin) {
    __shared__ int lcnt[BINSIZE];
    __shared__ int lscan[BINSIZE];
    __shared__ int lcur[BINSIZE];
    int b = blockIdx.x;
    int t = threadIdx.x;
    int n0 = b << BINSHIFT;
    int e0 = binptr[b];
    int e1 = binptr[b + 1];

    lcnt[t] = 0;
    __syncthreads();
    for (int i = e0 + t; i < e1; i += 256)
        atomicAdd(&lcnt[((unsigned)ebuf[i]) >> 24], 1);
    __syncthreads();

    int v = lcnt[t];
    lscan[t] = v;
    __syncthreads();
    for (int off = 1; off < 256; off <<= 1) {
        int tv = (t >= off) ? lscan[t - off] : 0;
        __syncthreads();
        lscan[t] += tv;
        __syncthreads();
    }
    int excl = e0 + lscan[t] - v;
    lcur[t] = excl;
    if (n0 + t < N) {
        rowptr[n0 + t] = excl;
        dinv[n0 + t] = 1.0f / sqrtf((float)(v + 1));
    }
    if (b == nbin - 1 && t == 0) rowptr[N] = E;
    __syncthreads();

    for (int i = e0 + t; i < e1; i += 256) {
        int w = ebuf[i];
        int dl = ((unsigned)w) >> 24;
        int p = atomicAdd(&lcur[dl], 1);
        col[p] = w & 0xFFFFFF;
    }
}

// ---------------- GEMM + dinv row-scale, chunked output ----------------
// G layout: [8 chunks][N][8 floats]; element (n,j) at ((j>>3)*N + n)*8 + (j&7).
// CHIN: input H also chunked (intermediate layers); else row-major [N][K].
template <int K, bool CHIN>
__global__ __launch_bounds__(256, 4) void gemm_scale_k(
    const float* __restrict__ H, const float* __restrict__ W,
    const float* __restrict__ dinv, float* __restrict__ G, int N) {
    __shared__ float Ws[K * EMB];
    int t = threadIdx.x;
    for (int i = t * 4; i < K * EMB; i += 1024) {
        *(float4*)(Ws + i) = *(const float4*)(W + i);
    }
    __syncthreads();

    int tc = t & 15;   // col group -> 4 cols
    int tr = t >> 4;   // row group -> 4 rows
    int j0 = tc * 4;
    int r0 = blockIdx.x * 64 + tr * 4;
    if (r0 >= N) return;

    int r[4];
#pragma unroll
    for (int i = 0; i < 4; i++) r[i] = (r0 + i < N) ? (r0 + i) : (N - 1);

#define ALOAD(i, k) (CHIN ? *(const float4*)(H + ((size_t)((k) >> 3) * N + r[i]) * 8 + ((k) & 7)) \
                          : *(const float4*)(H + (size_t)r[i] * K + (k)))

    float acc[4][4] = {{0.f}};
    float4 a[4], an[4];
#pragma unroll
    for (int i = 0; i < 4; i++) a[i] = ALOAD(i, 0);

#pragma unroll 1
    for (int k = 0; k < K; k += 4) {
        if (k + 4 < K) {
#pragma unroll
            for (int i = 0; i < 4; i++) an[i] = ALOAD(i, k + 4);
        }
#pragma unroll
        for (int kk = 0; kk < 4; kk++) {
            float4 wv = *(const float4*)(Ws + (k + kk) * EMB + j0);
#pragma unroll
            for (int i = 0; i < 4; i++) {
                float av = (kk == 0) ? a[i].x : (kk == 1) ? a[i].y : (kk == 2) ? a[i].z : a[i].w;
                acc[i][0] = fmaf(av, wv.x, acc[i][0]);
                acc[i][1] = fmaf(av, wv.y, acc[i][1]);
                acc[i][2] = fmaf(av, wv.z, acc[i][2]);
                acc[i][3] = fmaf(av, wv.w, acc[i][3]);
            }
        }
#pragma unroll
        for (int i = 0; i < 4; i++) a[i] = an[i];
    }
#undef ALOAD

#pragma unroll
    for (int i = 0; i < 4; i++) {
        if (r0 + i < N) {
            float s = dinv[r0 + i];
            float4 o = make_float4(acc[i][0] * s, acc[i][1] * s, acc[i][2] * s, acc[i][3] * s);
            *(float4*)(G + ((size_t)(j0 >> 3) * N + (r0 + i)) * 8 + (j0 & 7)) = o;
        }
    }
}

// ---------------- Chunked aggregation, 8 node-slots per wave ----------------
// chunk = blockIdx&7 -> XCD round-robin affinity (3.2MB chunk lives in that
// XCD's 4MB L2). Wave: slot=lane>>3 walks one node's edge list, f=lane&7 is
// the feature within the chunk; 8 consecutive nodes per wave-group -> the
// epilogue store is one 256B coalesced write. Each wave does AGG_GROUPS
// groups sequentially; no cross-lane reduction needed.

template <bool ROWMAJOR_OUT>
__global__ __launch_bounds__(256) void agg_slot_k(
    const float* __restrict__ G, const float* __restrict__ dinv,
    const int* __restrict__ rowptr, const int* __restrict__ col,
    const float* __restrict__ bias, float* __restrict__ Hout, int N) {
    int chunk = blockIdx.x & 7;
    int wave = threadIdx.x >> 6;
    int lane = threadIdx.x & 63;
    int slot = lane >> 3, f = lane & 7;
    const float* Gc = G + (size_t)chunk * N * 8;
    float bia = bias[chunk * 8 + f];

    int blk0 = (blockIdx.x >> 3) * (4 * 8 * AGG_GROUPS);  // block's base node

#pragma unroll 1
    for (int g = 0; g < AGG_GROUPS; g++) {
        int n0 = blk0 + (wave * AGG_GROUPS + g) * 8;
        int node = n0 + slot;
        bool valid = node < N;
        int s = 0, e = 0;
        float acc = 0.f;
        if (valid) {
            s = rowptr[node];
            e = rowptr[node + 1];
            acc = Gc[(size_t)node * 8 + f];   // self loop
        }
        float acc1 = 0.f;
        int i = s;
#pragma unroll 1
        for (; i + 2 <= e; i += 2) {
            int c0 = col[i];
            int c1 = col[i + 1];
            acc  += Gc[(size_t)c0 * 8 + f];
            acc1 += Gc[(size_t)c1 * 8 + f];
        }
        if (i < e) acc += Gc[(size_t)col[i] * 8 + f];
        acc += acc1;
        if (valid) {
            float v = acc * dinv[node] + bia;
            if (ROWMAJOR_OUT)
                Hout[(size_t)node * EMB + chunk * 8 + f] = v;
            else
                Hout[((size_t)chunk * N + node) * 8 + f] = v;
        }
    }
}

// Out = Y @ Wout + bout. Wave per node.
__global__ __launch_bounds__(256) void out_proj_k(
    const float* __restrict__ Y, const float* __restrict__ Wout,
    const float* __restrict__ bout, float* __restrict__ Out, int N) {
    int gw = (blockIdx.x * 256 + threadIdx.x) >> 6;
    int lane = threadIdx.x & 63;
    if (gw >= N) return;
    float p = Y[(size_t)gw * EMB + lane] * Wout[lane];
#pragma unroll
    for (int off = 32; off > 0; off >>= 1) p += __shfl_down(p, off, 64);
    if (lane == 0) Out[gw] = p + bout[0];
}

// ---------------- launch ----------------

extern "C" void kernel_launch(void* const* d_in, const int* in_sizes, int n_in,
                              void* d_out, int out_size, void* d_ws, size_t ws_size,
                              hipStream_t stream) {
    const float* x    = (const float*)d_in[0];
    const int*   ei   = (const int*)d_in[1];
    const float* W0   = (const float*)d_in[3];
    const float* b0   = (const float*)d_in[4];
    const float* W1   = (const float*)d_in[5];
    const float* b1   = (const float*)d_in[6];
    const float* W2   = (const float*)d_in[7];
    const float* b2   = (const float*)d_in[8];
    const float* W3   = (const float*)d_in[9];
    const float* b3   = (const float*)d_in[10];
    const float* Wout = (const float*)d_in[11];
    const float* bout = (const float*)d_in[12];

    const int N = in_sizes[0] / FEAT;      // 100000
    const int E = in_sizes[1] / 2;         // 3200000
    const int* srcp = ei;                  // edge_index[0]
    const int* dstp = ei + E;              // edge_index[1]
    const int nbin = (N + BINSIZE - 1) / BINSIZE;   // 391

    // workspace layout (regions padded to 64 elems for float4 alignment)
    const int NP = ((N + 64) + 63) / 64 * 64;   // holds N+1
    float* dinv  = (float*)d_ws;
    int* rowptr  = (int*)(dinv + NP);
    int* bincnt  = rowptr + NP;
    int* binptr  = bincnt + 1024;
    int* bincur  = binptr + 1024;
    int* col     = bincur + 1024;
    float* bufA  = (float*)(col + ((E + 63) / 64) * 64);  // chunked G
    int* ebuf    = (int*)bufA;            // aliased: ebuf dead before first gemm

    float* Out = (float*)d_out;
    float* Y   = Out + N;                 // y-region: chunked mid-layers, row-major at end

    const int gemm_blocks = (N + 63) / 64;
    const int nodes_per_blk = 4 * 8 * AGG_GROUPS;   // 4 waves x 8 slots x groups
    const int agg_blocks = ((N + nodes_per_blk - 1) / nodes_per_blk) * 8;
    const int proj_blocks = (N + 3) / 4;
    const int nchunk = (E + CHUNK - 1) / CHUNK;

    // --- CSR build ---
    zero_k<<<1, 1024, 0, stream>>>(bincnt, 1024);
    bin_count_k<<<nchunk, 256, 0, stream>>>(dstp, bincnt, E);
    binscan_k<<<1, 512, 0, stream>>>(bincnt, binptr, bincur, nbin, E);
    bin_edges_k<<<nchunk, 256, 0, stream>>>(srcp, dstp, bincur, ebuf, E);
    build_csr_k<<<nbin, 256, 0, stream>>>(ebuf, binptr, rowptr, dinv, col, N, E, nbin);

    // --- layer 0 (K=128, row-major in, chunked out) ---
    gemm_scale_k<FEAT, false><<<gemm_blocks, 256, 0, stream>>>(x, W0, dinv, bufA, N);
    agg_slot_k<false><<<agg_blocks, 256, 0, stream>>>(bufA, dinv, rowptr, col, b0, Y, N);
    // --- layer 1 ---
    gemm_scale_k<EMB, true><<<gemm_blocks, 256, 0, stream>>>(Y, W1, dinv, bufA, N);
    agg_slot_k<false><<<agg_blocks, 256, 0, stream>>>(bufA, dinv, rowptr, col, b1, Y, N);
    // --- layer 2 ---
    gemm_scale_k<EMB, true><<<gemm_blocks, 256, 0, stream>>>(Y, W2, dinv, bufA, N);
    agg_slot_k<false><<<agg_blocks, 256, 0, stream>>>(bufA, dinv, rowptr, col, b2, Y, N);
    // --- layer 3: row-major Y out + projection ---
    gemm_scale_k<EMB, true><<<gemm_blocks, 256, 0, stream>>>(Y, W3, dinv, bufA, N);
    agg_slot_k<true><<<agg_blocks, 256, 0, stream>>>(bufA, dinv, rowptr, col, b3, Y, N);
    out_proj_k<<<proj_blocks, 256, 0, stream>>>(Y, Wout, bout, Out, N);
}